// Round 17
// baseline (199.832 us; speedup 1.0000x reference)
//
#include <hip/hip_runtime.h>
#include <hip/hip_fp16.h>

#define N_NODES 100000
#define N_EDGES 3200000
#define N_GRAPHS 64
#define F 16

#define NBUCK 256
#define CPB 391                 // cols per bucket: 256*391 = 100096 >= N_NODES
#define NBLK 256                // fill segments (write-amp structure)
#define EPB ((N_EDGES + NBLK - 1) / NBLK)   // 12500 edges per block (exact, %4==0)
#define RMASK 0x1FFFF
#define PCHUNK 64               // nodes per gpool block

// ext_vector types accepted by __builtin_nontemporal_load (HIP_vector_type is not)
typedef float  f4v __attribute__((ext_vector_type(4)));
typedef float  f2v __attribute__((ext_vector_type(2)));
typedef unsigned u4v __attribute__((ext_vector_type(4)));

// Pass 1: per-block LDS histograms of col/row buckets; 1024 threads for latency hiding.
__global__ __launch_bounds__(1024) void k_histAB(const int* __restrict__ row,
                                                 const int* __restrict__ col,
                                                 int* __restrict__ cntmatC,
                                                 int* __restrict__ cntmatR,
                                                 int* __restrict__ bhistC,
                                                 int* __restrict__ bhistR) {
    __shared__ int lhc[NBUCK], lhr[NBUCK];
    for (int i = threadIdx.x; i < NBUCK; i += 1024) { lhc[i] = 0; lhr[i] = 0; }
    __syncthreads();
    int beg = blockIdx.x * EPB;                // EPB and beg are multiples of 4
    const int4* r4 = (const int4*)(row + beg);
    const int4* c4 = (const int4*)(col + beg);
    const int n4 = EPB / 4;
    for (int i = threadIdx.x; i < n4; i += 1024) {
        int4 r = r4[i], c = c4[i];
        atomicAdd(&lhc[(unsigned)c.x / CPB], 1);
        atomicAdd(&lhc[(unsigned)c.y / CPB], 1);
        atomicAdd(&lhc[(unsigned)c.z / CPB], 1);
        atomicAdd(&lhc[(unsigned)c.w / CPB], 1);
        atomicAdd(&lhr[(unsigned)r.x / CPB], 1);
        atomicAdd(&lhr[(unsigned)r.y / CPB], 1);
        atomicAdd(&lhr[(unsigned)r.z / CPB], 1);
        atomicAdd(&lhr[(unsigned)r.w / CPB], 1);
    }
    __syncthreads();
    for (int i = threadIdx.x; i < NBUCK; i += 1024) {
        int c = lhc[i], r = lhr[i];
        cntmatC[i * NBLK + blockIdx.x] = c;
        cntmatR[i * NBLK + blockIdx.x] = r;
        if (c) atomicAdd(&bhistC[i], c);
        if (r) atomicAdd(&bhistR[i], r);
    }
}

// Pass 2 (merged): blocks 0-511 scan cntmat rows; blocks 512/513 scan bucket totals.
__global__ __launch_bounds__(256) void k_scans(int* __restrict__ cntmatC,
                                               int* __restrict__ cntmatR,
                                               const int* __restrict__ bhistC,
                                               const int* __restrict__ bhistR,
                                               int* __restrict__ bbaseC,
                                               int* __restrict__ bbaseR) {
    __shared__ int sd[256];
    int t = threadIdx.x;
    if (blockIdx.x < 2 * NBUCK) {
        int which = blockIdx.x >> 8;
        int b = blockIdx.x & 255;
        int* cm = which ? cntmatR : cntmatC;
        int v = cm[b * NBLK + t];
        sd[t] = v;
        __syncthreads();
        for (int off = 1; off < 256; off <<= 1) {
            int a = (t >= off) ? sd[t - off] : 0;
            __syncthreads();
            sd[t] += a;
            __syncthreads();
        }
        cm[b * NBLK + t] = sd[t] - v;
    } else {
        const int* h = (blockIdx.x == 2 * NBUCK) ? bhistC : bhistR;
        int* o = (blockIdx.x == 2 * NBUCK) ? bbaseC : bbaseR;
        int v = (h[t] + 15) & ~15;
        sd[t] = v;
        __syncthreads();
        for (int off = 1; off < NBUCK; off <<= 1) {
            int a = (t >= off) ? sd[t - off] : 0;
            __syncthreads();
            sd[t] += a;
            __syncthreads();
        }
        o[t] = sd[t] - v;
    }
}

// Pass 3: dual deterministic scatter (int4 reads, 1024 threads)
__global__ __launch_bounds__(1024) void k_fill3(const int* __restrict__ row,
                                                const int* __restrict__ col,
                                                const int* __restrict__ cntmatC,
                                                const int* __restrict__ cntmatR,
                                                const int* __restrict__ bbaseC,
                                                const int* __restrict__ bbaseR,
                                                unsigned* __restrict__ recsA,
                                                unsigned short* __restrict__ rrecs) {
    __shared__ int ptrC[NBUCK], ptrR[NBUCK];
    for (int i = threadIdx.x; i < NBUCK; i += 1024) {
        ptrC[i] = bbaseC[i] + cntmatC[i * NBLK + blockIdx.x];
        ptrR[i] = bbaseR[i] + cntmatR[i * NBLK + blockIdx.x];
    }
    __syncthreads();
    int beg = blockIdx.x * EPB;
    const int4* r4 = (const int4*)(row + beg);
    const int4* c4 = (const int4*)(col + beg);
    const int n4 = EPB / 4;
    for (int i = threadIdx.x; i < n4; i += 1024) {
        int4 rv = r4[i], cv = c4[i];
        int rr[4] = {rv.x, rv.y, rv.z, rv.w};
        int cc[4] = {cv.x, cv.y, cv.z, cv.w};
#pragma unroll
        for (int u = 0; u < 4; ++u) {
            unsigned c = (unsigned)cc[u];
            unsigned r = (unsigned)rr[u];
            unsigned bc = c / CPB;
            int slot = atomicAdd(&ptrC[bc], 1);
            recsA[slot] = ((c - bc * CPB) << 17) | r;
            unsigned br = r / CPB;
            int slotR = atomicAdd(&ptrR[br], 1);
            rrecs[slotR] = (unsigned short)(r - br * CPB);
        }
    }
}

// Pass 4 (merged, 512 threads): blocks 0-255: per-col-bucket counting sort -> recsB/rowptr/cnt_in
//                               blocks 256-511: per-row-bucket degree histogram -> dinv + wx
__global__ __launch_bounds__(512) void k_degsort(const unsigned* __restrict__ recsA,
                                                 const int* __restrict__ bbaseC,
                                                 const int* __restrict__ bhistC,
                                                 unsigned* __restrict__ recsB,
                                                 int* __restrict__ rowptr,
                                                 int* __restrict__ cnt_in,
                                                 const unsigned short* __restrict__ rrecs,
                                                 const int* __restrict__ bbaseR,
                                                 const int* __restrict__ bhistR,
                                                 const float* __restrict__ x,
                                                 float* __restrict__ dinv,
                                                 float4* __restrict__ wx) {
    __shared__ int hist[CPB];
    __shared__ int scn[512];
    __shared__ int off[CPB];
    int t = threadIdx.x;
    if (blockIdx.x < NBUCK) {
        int b = blockIdx.x;
        if (t < CPB) hist[t] = 0;
        __syncthreads();
        int beg = bbaseC[b], n = bhistC[b];
        for (int i = t; i < n; i += 512)
            atomicAdd(&hist[recsA[beg + i] >> 17], 1);
        __syncthreads();
        int v = (t < CPB) ? hist[t] : 0;
        scn[t] = v;
        __syncthreads();
        for (int o = 1; o < 512; o <<= 1) {
            int a = (t >= o) ? scn[t - o] : 0;
            __syncthreads();
            scn[t] += a;
            __syncthreads();
        }
        if (t < CPB) {
            int ex = scn[t] - v;
            off[t] = ex;
            int node = b * CPB + t;
            if (node < N_NODES) { rowptr[node] = beg + ex; cnt_in[node] = v; }
        }
        __syncthreads();
        for (int i = t; i < n; i += 512) {
            unsigned rec = recsA[beg + i];
            int d = atomicAdd(&off[rec >> 17], 1);
            recsB[beg + d] = rec;
        }
    } else {
        int b = blockIdx.x - NBUCK;
        if (t < CPB) hist[t] = 0;
        __syncthreads();
        int beg = bbaseR[b], n = bhistR[b];
        for (int i = t; i < n; i += 512)
            atomicAdd(&hist[rrecs[beg + i]], 1);
        __syncthreads();
        if (t < CPB) {
            int node = b * CPB + t;
            if (node < N_NODES) {
                int d = hist[t];
                float di = d > 0 ? rsqrtf((float)d) : 0.0f;
                dinv[node] = di;
                wx[node] = make_float4(di * x[node * 3 + 0], di * x[node * 3 + 1],
                                       di * x[node * 3 + 2], 0.0f);
            }
        }
    }
}

// Fused conv1: 8-deep gather with L1-bypass (nontemporal) wx reads,
// then the two 16-wide node matmuls.
__global__ __launch_bounds__(256) void k_conv1(const unsigned* __restrict__ recsB,
                                               const int* __restrict__ rowptr,
                                               const int* __restrict__ cnt_in,
                                               const float* __restrict__ dinv,
                                               const float4* __restrict__ wx,
                                               const float* __restrict__ x,
                                               const float* __restrict__ c1W1,
                                               const float* __restrict__ c1b1,
                                               const float* __restrict__ c1W2,
                                               const float* __restrict__ c2W1,
                                               const float* __restrict__ c2b1,
                                               const float* __restrict__ c2W2,
                                               float* __restrict__ center2,
                                               __half* __restrict__ xj2h) {
    int nn = blockIdx.x * blockDim.x + threadIdx.x;
    if (nn >= N_NODES) return;
    int beg = rowptr[nn], c = cnt_in[nn], end = beg + c;
    const f4v* wxv = reinterpret_cast<const f4v*>(wx);
    float a0 = 0.0f, a1 = 0.0f, a2 = 0.0f;
    int j = beg;
    for (; j + 7 < end; j += 8) {
        int r[8];
#pragma unroll
        for (int u = 0; u < 8; ++u) r[u] = recsB[j + u] & RMASK;
        f4v v[8];
#pragma unroll
        for (int u = 0; u < 8; ++u) v[u] = __builtin_nontemporal_load(&wxv[r[u]]);
#pragma unroll
        for (int u = 0; u < 8; ++u) { a0 += v[u].x; a1 += v[u].y; a2 += v[u].z; }
    }
    if (j < end) {   // predicated tail (<=7), one round-trip
        int r[7]; bool ok[7];
#pragma unroll
        for (int u = 0; u < 7; ++u) {
            ok[u] = (j + u) < end;
            r[u] = recsB[ok[u] ? j + u : j] & RMASK;
        }
#pragma unroll
        for (int u = 0; u < 7; ++u) {
            if (ok[u]) {
                f4v v = __builtin_nontemporal_load(&wxv[r[u]]);
                a0 += v.x; a1 += v.y; a2 += v.z;
            }
        }
    }
    float sc = dinv[nn] / (float)(c > 1 ? c : 1);
    float y0 = a0 * sc, y1 = a1 * sc, y2 = a2 * sc;
    float x0 = x[nn * 3 + 0], x1 = x[nn * 3 + 1], x2 = x[nn * 3 + 2];
    float h[F];
#pragma unroll
    for (int k = 0; k < F; ++k) {
        float v = c1b1[k]
                + x0 * c1W1[0 * F + k] + x1 * c1W1[1 * F + k] + x2 * c1W1[2 * F + k]
                + y0 * c1W2[0 * F + k] + y1 * c1W2[1 * F + k] + y2 * c1W2[2 * F + k];
        h[k] = v > 0.0f ? v : 0.0f;
    }
    float di = dinv[nn];
    float cc[F];
    union { __half hh[F]; uint4 v4[2]; } u;
#pragma unroll
    for (int k = 0; k < F; ++k) {
        float c2 = c2b1[k];
        float xx = 0.0f;
#pragma unroll
        for (int i = 0; i < F; ++i) {
            c2 += h[i] * c2W1[i * F + k];
            xx += h[i] * c2W2[i * F + k];
        }
        cc[k] = c2;
        u.hh[k] = __float2half_rn(di * xx);
    }
    float4* cd = (float4*)(center2 + nn * F);
#pragma unroll
    for (int q = 0; q < 4; ++q)
        cd[q] = make_float4(cc[q * 4 + 0], cc[q * 4 + 1], cc[q * 4 + 2], cc[q * 4 + 3]);
    uint4* xd = (uint4*)(xj2h + nn * F);
    xd[0] = u.v4[0];
    xd[1] = u.v4[1];
}

// Fused conv2-aggregation + pooling: 128 threads = 64 nodes x 2 uint4-lanes.
// xj2h and center2 reads are nontemporal (L1 bypass -> deeper outstanding-miss queue).
__global__ __launch_bounds__(128) void k_gpool(const unsigned* __restrict__ recsB,
                                               const int* __restrict__ rowptr,
                                               const int* __restrict__ cnt_in,
                                               const float* __restrict__ dinv,
                                               const __half* __restrict__ xj2h,
                                               const float* __restrict__ center2,
                                               const int* __restrict__ batch,
                                               float* __restrict__ gpool,
                                               int* __restrict__ gcnt) {
    __shared__ float tile[PCHUNK][F + 1];
    __shared__ int bid[PCHUNK];
    int g = threadIdx.x >> 1, h = threadIdx.x & 1;   // 64 groups of 2 lanes
    int nn = blockIdx.x * PCHUNK + g;
    bool valid = nn < N_NODES;
    if (valid) {
        int beg = rowptr[nn], c = cnt_in[nn], end = beg + c;
        const __half* base = xj2h + 8 * h;
        float2 ac[4];
#pragma unroll
        for (int q = 0; q < 4; ++q) ac[q] = make_float2(0.0f, 0.0f);
        int j = beg;
        for (; j + 3 < end; j += 4) {
            int r[4];
#pragma unroll
            for (int u = 0; u < 4; ++u) r[u] = recsB[j + u] & RMASK;
            u4v v[4];
#pragma unroll
            for (int u = 0; u < 4; ++u)
                v[u] = __builtin_nontemporal_load(
                    reinterpret_cast<const u4v*>(base + r[u] * F));
#pragma unroll
            for (int u = 0; u < 4; ++u) {
                union { u4v q4; __half2 hh[4]; } w; w.q4 = v[u];
#pragma unroll
                for (int q = 0; q < 4; ++q) {
                    float2 f = __half22float2(w.hh[q]);
                    ac[q].x += f.x; ac[q].y += f.y;
                }
            }
        }
        if (j < end) {   // predicated tail (<=3), one round-trip
            int r[3]; bool ok[3];
#pragma unroll
            for (int u = 0; u < 3; ++u) {
                ok[u] = (j + u) < end;
                r[u] = recsB[ok[u] ? j + u : j] & RMASK;
            }
            u4v v[3];
#pragma unroll
            for (int u = 0; u < 3; ++u)
                v[u] = __builtin_nontemporal_load(
                    reinterpret_cast<const u4v*>(base + r[u] * F));
#pragma unroll
            for (int u = 0; u < 3; ++u) {
                if (ok[u]) {
                    union { u4v q4; __half2 hh[4]; } w; w.q4 = v[u];
#pragma unroll
                    for (int q = 0; q < 4; ++q) {
                        float2 f = __half22float2(w.hh[q]);
                        ac[q].x += f.x; ac[q].y += f.y;
                    }
                }
            }
        }
        float sc = dinv[nn] / (float)(c > 1 ? c : 1);
        const f2v* ctr = reinterpret_cast<const f2v*>(center2 + nn * F + 8 * h);
#pragma unroll
        for (int q = 0; q < 4; ++q) {
            f2v cv = __builtin_nontemporal_load(&ctr[q]);
            float v0 = cv.x + ac[q].x * sc; v0 = v0 > 0.0f ? v0 : 0.0f;
            float v1 = cv.y + ac[q].y * sc; v1 = v1 > 0.0f ? v1 : 0.0f;
            tile[g][8 * h + 2 * q]     = v0;
            tile[g][8 * h + 2 * q + 1] = v1;
        }
    }
    if (h == 0) {
        int bb = -1;
        if (valid) bb = batch[nn];
        bid[g] = bb;
    }
    __syncthreads();
    if (threadIdx.x < 16) {
        int kk = threadIdx.x;
        int bcur = -2; float acc = 0.0f; int run = 0;
        for (int gg = 0; gg < PCHUNK; ++gg) {
            int b = bid[gg];
            if (b < 0) break;   // tail: invalid nodes only at the end
            if (b != bcur) {
                if (bcur >= 0) {
                    atomicAdd(&gpool[bcur * F + kk], acc);
                    if (kk == 0) atomicAdd(&gcnt[bcur], run);
                }
                acc = 0.0f; run = 0; bcur = b;
            }
            acc += tile[gg][kk];
            ++run;
        }
        if (bcur >= 0) {
            atomicAdd(&gpool[bcur * F + kk], acc);
            if (kk == 0) atomicAdd(&gcnt[bcur], run);
        }
    }
}

__global__ __launch_bounds__(64) void k_mlp(const float* __restrict__ gpool,
                                            const int* __restrict__ gcnt,
                                            const float* __restrict__ l1W,
                                            const float* __restrict__ l1b,
                                            const float* __restrict__ l2W,
                                            const float* __restrict__ l2b,
                                            float* __restrict__ out) {
    int g = threadIdx.x;
    if (g >= N_GRAPHS) return;
    int c = gcnt[g];
    float ic = 1.0f / (float)(c > 1 ? c : 1);
    float v[F], h[F];
#pragma unroll
    for (int k = 0; k < F; ++k) v[k] = gpool[g * F + k] * ic;
#pragma unroll
    for (int k = 0; k < F; ++k) {
        float a = l1b[k];
#pragma unroll
        for (int i = 0; i < F; ++i) a += v[i] * l1W[i * F + k];
        h[k] = a > 0.0f ? a : 0.0f;
    }
#pragma unroll
    for (int j = 0; j < 2; ++j) {
        float a = l2b[j];
#pragma unroll
        for (int i = 0; i < F; ++i) a += h[i] * l2W[i * 2 + j];
        out[g * 2 + j] = a;
    }
}

extern "C" void kernel_launch(void* const* d_in, const int* in_sizes, int n_in,
                              void* d_out, int out_size, void* d_ws, size_t ws_size,
                              hipStream_t stream) {
    const float* x     = (const float*)d_in[0];
    const int*   ei    = (const int*)d_in[1];
    const int*   row   = ei;
    const int*   col   = ei + N_EDGES;
    const int*   batch = (const int*)d_in[2];
    const float* c1W1  = (const float*)d_in[3];
    const float* c1b1  = (const float*)d_in[4];
    const float* c1W2  = (const float*)d_in[5];
    const float* c2W1  = (const float*)d_in[6];
    const float* c2b1  = (const float*)d_in[7];
    const float* c2W2  = (const float*)d_in[8];
    const float* l1W   = (const float*)d_in[9];
    const float* l1b   = (const float*)d_in[10];
    const float* l2W   = (const float*)d_in[11];
    const float* l2b   = (const float*)d_in[12];
    float* out = (float*)d_out;

    char* p = (char*)d_ws;
    auto alloc = [&p](size_t bytes) -> void* {
        void* r = (void*)p;
        p += (bytes + 255) & ~(size_t)255;
        return r;
    };
    float*          dinv    = (float*)         alloc(N_NODES * 4);
    float4*         wx      = (float4*)        alloc((size_t)N_NODES * 16);
    float*          center2 = (float*)         alloc((size_t)N_NODES * F * 4);
    __half*         xj2h    = (__half*)        alloc((size_t)N_NODES * F * 2);
    // gpool(4KB) + gcnt(256B) contiguous -> one memset
    float*          gpool   = (float*)         alloc(N_GRAPHS * F * 4);
    int*            gcnt    = (int*)           alloc(N_GRAPHS * 4);
    // bhistC(1KB) + bhistR(1KB) contiguous -> one memset
    int*            bhistC  = (int*)           alloc(NBUCK * 4);
    int*            bhistR  = (int*)           alloc(NBUCK * 4);
    int*            bbaseC  = (int*)           alloc((NBUCK + 1) * 4);
    int*            bbaseR  = (int*)           alloc((NBUCK + 1) * 4);
    int*            cntmatC = (int*)           alloc((size_t)NBUCK * NBLK * 4);
    int*            cntmatR = (int*)           alloc((size_t)NBUCK * NBLK * 4);
    int*            rowptr  = (int*)           alloc((size_t)N_NODES * 4);
    int*            cnt_in  = (int*)           alloc((size_t)N_NODES * 4);
    unsigned*       recsA   = (unsigned*)      alloc(((size_t)N_EDGES + NBUCK * 16) * 4);
    unsigned*       recsB   = (unsigned*)      alloc(((size_t)N_EDGES + NBUCK * 16) * 4);
    unsigned short* rrecs   = (unsigned short*)alloc(((size_t)N_EDGES + NBUCK * 16) * 2);

    hipMemsetAsync(gpool, 0, N_GRAPHS * F * 4 + 256, stream);     // gpool + gcnt
    hipMemsetAsync(bhistC, 0, 2 * NBUCK * 4, stream);             // bhistC + bhistR

    k_histAB<<<NBLK, 1024, 0, stream>>>(row, col, cntmatC, cntmatR, bhistC, bhistR);
    k_scans<<<2 * NBUCK + 2, 256, 0, stream>>>(cntmatC, cntmatR, bhistC, bhistR, bbaseC, bbaseR);
    k_fill3<<<NBLK, 1024, 0, stream>>>(row, col, cntmatC, cntmatR, bbaseC, bbaseR, recsA, rrecs);
    k_degsort<<<2 * NBUCK, 512, 0, stream>>>(recsA, bbaseC, bhistC, recsB, rowptr, cnt_in,
                                             rrecs, bbaseR, bhistR, x, dinv, wx);
    k_conv1<<<(N_NODES + 255) / 256, 256, 0, stream>>>(recsB, rowptr, cnt_in, dinv, wx, x,
                                                       c1W1, c1b1, c1W2, c2W1, c2b1, c2W2,
                                                       center2, xj2h);
    k_gpool<<<(N_NODES + PCHUNK - 1) / PCHUNK, 128, 0, stream>>>(
        recsB, rowptr, cnt_in, dinv, xj2h, center2, batch, gpool, gcnt);
    k_mlp<<<1, 64, 0, stream>>>(gpool, gcnt, l1W, l1b, l2W, l2b, out);
}

// Round 18
// 146.241 us; speedup vs baseline: 1.3665x; 1.3665x over previous
//
#include <hip/hip_runtime.h>
#include <hip/hip_fp16.h>

#define N_NODES 100000
#define N_EDGES 3200000
#define N_GRAPHS 64
#define F 16

#define NBUCK 256
#define CPB 391                 // cols per bucket: 256*391 = 100096 >= N_NODES
#define NBLK 256                // fill segments (write-amp structure)
#define EPB ((N_EDGES + NBLK - 1) / NBLK)   // 12500 edges per block (exact, %4==0)
#define RMASK 0x1FFFF
#define PCHUNK 64               // nodes per gpool block

// Pass 1: per-block LDS histograms of col/row buckets; 1024 threads for latency hiding.
__global__ __launch_bounds__(1024) void k_histAB(const int* __restrict__ row,
                                                 const int* __restrict__ col,
                                                 int* __restrict__ cntmatC,
                                                 int* __restrict__ cntmatR,
                                                 int* __restrict__ bhistC,
                                                 int* __restrict__ bhistR) {
    __shared__ int lhc[NBUCK], lhr[NBUCK];
    for (int i = threadIdx.x; i < NBUCK; i += 1024) { lhc[i] = 0; lhr[i] = 0; }
    __syncthreads();
    int beg = blockIdx.x * EPB;                // EPB and beg are multiples of 4
    const int4* r4 = (const int4*)(row + beg);
    const int4* c4 = (const int4*)(col + beg);
    const int n4 = EPB / 4;
    for (int i = threadIdx.x; i < n4; i += 1024) {
        int4 r = r4[i], c = c4[i];
        atomicAdd(&lhc[(unsigned)c.x / CPB], 1);
        atomicAdd(&lhc[(unsigned)c.y / CPB], 1);
        atomicAdd(&lhc[(unsigned)c.z / CPB], 1);
        atomicAdd(&lhc[(unsigned)c.w / CPB], 1);
        atomicAdd(&lhr[(unsigned)r.x / CPB], 1);
        atomicAdd(&lhr[(unsigned)r.y / CPB], 1);
        atomicAdd(&lhr[(unsigned)r.z / CPB], 1);
        atomicAdd(&lhr[(unsigned)r.w / CPB], 1);
    }
    __syncthreads();
    for (int i = threadIdx.x; i < NBUCK; i += 1024) {
        int c = lhc[i], r = lhr[i];
        cntmatC[i * NBLK + blockIdx.x] = c;
        cntmatR[i * NBLK + blockIdx.x] = r;
        if (c) atomicAdd(&bhistC[i], c);
        if (r) atomicAdd(&bhistR[i], r);
    }
}

// Pass 2 (merged): blocks 0-511 scan cntmat rows; blocks 512/513 scan bucket totals.
__global__ __launch_bounds__(256) void k_scans(int* __restrict__ cntmatC,
                                               int* __restrict__ cntmatR,
                                               const int* __restrict__ bhistC,
                                               const int* __restrict__ bhistR,
                                               int* __restrict__ bbaseC,
                                               int* __restrict__ bbaseR) {
    __shared__ int sd[256];
    int t = threadIdx.x;
    if (blockIdx.x < 2 * NBUCK) {
        int which = blockIdx.x >> 8;
        int b = blockIdx.x & 255;
        int* cm = which ? cntmatR : cntmatC;
        int v = cm[b * NBLK + t];
        sd[t] = v;
        __syncthreads();
        for (int off = 1; off < 256; off <<= 1) {
            int a = (t >= off) ? sd[t - off] : 0;
            __syncthreads();
            sd[t] += a;
            __syncthreads();
        }
        cm[b * NBLK + t] = sd[t] - v;
    } else {
        const int* h = (blockIdx.x == 2 * NBUCK) ? bhistC : bhistR;
        int* o = (blockIdx.x == 2 * NBUCK) ? bbaseC : bbaseR;
        int v = (h[t] + 15) & ~15;
        sd[t] = v;
        __syncthreads();
        for (int off = 1; off < NBUCK; off <<= 1) {
            int a = (t >= off) ? sd[t - off] : 0;
            __syncthreads();
            sd[t] += a;
            __syncthreads();
        }
        o[t] = sd[t] - v;
    }
}

// Pass 3: dual deterministic scatter (int4 reads, 1024 threads)
__global__ __launch_bounds__(1024) void k_fill3(const int* __restrict__ row,
                                                const int* __restrict__ col,
                                                const int* __restrict__ cntmatC,
                                                const int* __restrict__ cntmatR,
                                                const int* __restrict__ bbaseC,
                                                const int* __restrict__ bbaseR,
                                                unsigned* __restrict__ recsA,
                                                unsigned short* __restrict__ rrecs) {
    __shared__ int ptrC[NBUCK], ptrR[NBUCK];
    for (int i = threadIdx.x; i < NBUCK; i += 1024) {
        ptrC[i] = bbaseC[i] + cntmatC[i * NBLK + blockIdx.x];
        ptrR[i] = bbaseR[i] + cntmatR[i * NBLK + blockIdx.x];
    }
    __syncthreads();
    int beg = blockIdx.x * EPB;
    const int4* r4 = (const int4*)(row + beg);
    const int4* c4 = (const int4*)(col + beg);
    const int n4 = EPB / 4;
    for (int i = threadIdx.x; i < n4; i += 1024) {
        int4 rv = r4[i], cv = c4[i];
        int rr[4] = {rv.x, rv.y, rv.z, rv.w};
        int cc[4] = {cv.x, cv.y, cv.z, cv.w};
#pragma unroll
        for (int u = 0; u < 4; ++u) {
            unsigned c = (unsigned)cc[u];
            unsigned r = (unsigned)rr[u];
            unsigned bc = c / CPB;
            int slot = atomicAdd(&ptrC[bc], 1);
            recsA[slot] = ((c - bc * CPB) << 17) | r;
            unsigned br = r / CPB;
            int slotR = atomicAdd(&ptrR[br], 1);
            rrecs[slotR] = (unsigned short)(r - br * CPB);
        }
    }
}

// Pass 4 (merged, 512 threads): blocks 0-255: per-col-bucket counting sort -> recsB/rowptr/cnt_in
//                               blocks 256-511: per-row-bucket degree histogram -> dinv + wx
__global__ __launch_bounds__(512) void k_degsort(const unsigned* __restrict__ recsA,
                                                 const int* __restrict__ bbaseC,
                                                 const int* __restrict__ bhistC,
                                                 unsigned* __restrict__ recsB,
                                                 int* __restrict__ rowptr,
                                                 int* __restrict__ cnt_in,
                                                 const unsigned short* __restrict__ rrecs,
                                                 const int* __restrict__ bbaseR,
                                                 const int* __restrict__ bhistR,
                                                 const float* __restrict__ x,
                                                 float* __restrict__ dinv,
                                                 float4* __restrict__ wx) {
    __shared__ int hist[CPB];
    __shared__ int scn[512];
    __shared__ int off[CPB];
    int t = threadIdx.x;
    if (blockIdx.x < NBUCK) {
        int b = blockIdx.x;
        if (t < CPB) hist[t] = 0;
        __syncthreads();
        int beg = bbaseC[b], n = bhistC[b];
        for (int i = t; i < n; i += 512)
            atomicAdd(&hist[recsA[beg + i] >> 17], 1);
        __syncthreads();
        int v = (t < CPB) ? hist[t] : 0;
        scn[t] = v;
        __syncthreads();
        for (int o = 1; o < 512; o <<= 1) {
            int a = (t >= o) ? scn[t - o] : 0;
            __syncthreads();
            scn[t] += a;
            __syncthreads();
        }
        if (t < CPB) {
            int ex = scn[t] - v;
            off[t] = ex;
            int node = b * CPB + t;
            if (node < N_NODES) { rowptr[node] = beg + ex; cnt_in[node] = v; }
        }
        __syncthreads();
        for (int i = t; i < n; i += 512) {
            unsigned rec = recsA[beg + i];
            int d = atomicAdd(&off[rec >> 17], 1);
            recsB[beg + d] = rec;
        }
    } else {
        int b = blockIdx.x - NBUCK;
        if (t < CPB) hist[t] = 0;
        __syncthreads();
        int beg = bbaseR[b], n = bhistR[b];
        for (int i = t; i < n; i += 512)
            atomicAdd(&hist[rrecs[beg + i]], 1);
        __syncthreads();
        if (t < CPB) {
            int node = b * CPB + t;
            if (node < N_NODES) {
                int d = hist[t];
                float di = d > 0 ? rsqrtf((float)d) : 0.0f;
                dinv[node] = di;
                wx[node] = make_float4(di * x[node * 3 + 0], di * x[node * 3 + 1],
                                       di * x[node * 3 + 2], 0.0f);
            }
        }
    }
}

// Fused conv1: software-pipelined 8-deep gather, then the two 16-wide node matmuls.
__global__ __launch_bounds__(256) void k_conv1(const unsigned* __restrict__ recsB,
                                               const int* __restrict__ rowptr,
                                               const int* __restrict__ cnt_in,
                                               const float* __restrict__ dinv,
                                               const float4* __restrict__ wx,
                                               const float* __restrict__ x,
                                               const float* __restrict__ c1W1,
                                               const float* __restrict__ c1b1,
                                               const float* __restrict__ c1W2,
                                               const float* __restrict__ c2W1,
                                               const float* __restrict__ c2b1,
                                               const float* __restrict__ c2W2,
                                               float* __restrict__ center2,
                                               __half* __restrict__ xj2h) {
    int nn = blockIdx.x * blockDim.x + threadIdx.x;
    if (nn >= N_NODES) return;
    int beg = rowptr[nn], c = cnt_in[nn], end = beg + c;
    float a0 = 0.0f, a1 = 0.0f, a2 = 0.0f;
    int nfull = c >> 3;
    int j = beg;
    int rc[8];
    if (nfull > 0) {
#pragma unroll
        for (int u = 0; u < 8; ++u) rc[u] = recsB[j + u] & RMASK;
    }
    for (int it = 0; it < nfull; ++it) {
        int jn = j + 8;
        bool more = (it + 1) < nfull;
        int rn[8];
#pragma unroll
        for (int u = 0; u < 8; ++u) rn[u] = recsB[more ? jn + u : j + u] & RMASK;
        float4 v[8];
#pragma unroll
        for (int u = 0; u < 8; ++u) v[u] = wx[rc[u]];
#pragma unroll
        for (int u = 0; u < 8; ++u) { a0 += v[u].x; a1 += v[u].y; a2 += v[u].z; }
        j = jn;
#pragma unroll
        for (int u = 0; u < 8; ++u) rc[u] = rn[u];
    }
    if (j < end) {   // predicated tail (<=7), one round-trip
        int r[7]; bool ok[7];
#pragma unroll
        for (int u = 0; u < 7; ++u) {
            ok[u] = (j + u) < end;
            r[u] = recsB[ok[u] ? j + u : j] & RMASK;
        }
#pragma unroll
        for (int u = 0; u < 7; ++u) {
            if (ok[u]) { float4 v = wx[r[u]]; a0 += v.x; a1 += v.y; a2 += v.z; }
        }
    }
    float sc = dinv[nn] / (float)(c > 1 ? c : 1);
    float y0 = a0 * sc, y1 = a1 * sc, y2 = a2 * sc;
    float x0 = x[nn * 3 + 0], x1 = x[nn * 3 + 1], x2 = x[nn * 3 + 2];
    float h[F];
#pragma unroll
    for (int k = 0; k < F; ++k) {
        float v = c1b1[k]
                + x0 * c1W1[0 * F + k] + x1 * c1W1[1 * F + k] + x2 * c1W1[2 * F + k]
                + y0 * c1W2[0 * F + k] + y1 * c1W2[1 * F + k] + y2 * c1W2[2 * F + k];
        h[k] = v > 0.0f ? v : 0.0f;
    }
    float di = dinv[nn];
    float cc[F];
    union { __half hh[F]; uint4 v4[2]; } u;
#pragma unroll
    for (int k = 0; k < F; ++k) {
        float c2 = c2b1[k];
        float xx = 0.0f;
#pragma unroll
        for (int i = 0; i < F; ++i) {
            c2 += h[i] * c2W1[i * F + k];
            xx += h[i] * c2W2[i * F + k];
        }
        cc[k] = c2;
        u.hh[k] = __float2half_rn(di * xx);
    }
    float4* cd = (float4*)(center2 + nn * F);
#pragma unroll
    for (int q = 0; q < 4; ++q)
        cd[q] = make_float4(cc[q * 4 + 0], cc[q * 4 + 1], cc[q * 4 + 2], cc[q * 4 + 3]);
    uint4* xd = (uint4*)(xj2h + nn * F);
    xd[0] = u.v4[0];
    xd[1] = u.v4[1];
}

// Fused conv2-aggregation + pooling: 128 threads = 64 nodes x 2 uint4-lanes.
// Lane h of a pair owns features 8h..8h+7; one uint4 load = its whole half-row.
__global__ __launch_bounds__(128) void k_gpool(const unsigned* __restrict__ recsB,
                                               const int* __restrict__ rowptr,
                                               const int* __restrict__ cnt_in,
                                               const float* __restrict__ dinv,
                                               const __half* __restrict__ xj2h,
                                               const float* __restrict__ center2,
                                               const int* __restrict__ batch,
                                               float* __restrict__ gpool,
                                               int* __restrict__ gcnt) {
    __shared__ float tile[PCHUNK][F + 1];
    __shared__ int bid[PCHUNK];
    int g = threadIdx.x >> 1, h = threadIdx.x & 1;   // 64 groups of 2 lanes
    int nn = blockIdx.x * PCHUNK + g;
    bool valid = nn < N_NODES;
    if (valid) {
        int beg = rowptr[nn], c = cnt_in[nn], end = beg + c;
        const __half* base = xj2h + 8 * h;
        float2 ac[4];
#pragma unroll
        for (int q = 0; q < 4; ++q) ac[q] = make_float2(0.0f, 0.0f);
        int j = beg;
        for (; j + 3 < end; j += 4) {
            int r[4];
#pragma unroll
            for (int u = 0; u < 4; ++u) r[u] = recsB[j + u] & RMASK;
            uint4 v[4];
#pragma unroll
            for (int u = 0; u < 4; ++u) v[u] = *(const uint4*)(base + r[u] * F);
#pragma unroll
            for (int u = 0; u < 4; ++u) {
                union { uint4 q4; __half2 hh[4]; } w; w.q4 = v[u];
#pragma unroll
                for (int q = 0; q < 4; ++q) {
                    float2 f = __half22float2(w.hh[q]);
                    ac[q].x += f.x; ac[q].y += f.y;
                }
            }
        }
        if (j < end) {   // predicated tail (<=3), one round-trip
            int r[3]; bool ok[3];
#pragma unroll
            for (int u = 0; u < 3; ++u) {
                ok[u] = (j + u) < end;
                r[u] = recsB[ok[u] ? j + u : j] & RMASK;
            }
            uint4 v[3];
#pragma unroll
            for (int u = 0; u < 3; ++u) v[u] = *(const uint4*)(base + r[u] * F);
#pragma unroll
            for (int u = 0; u < 3; ++u) {
                if (ok[u]) {
                    union { uint4 q4; __half2 hh[4]; } w; w.q4 = v[u];
#pragma unroll
                    for (int q = 0; q < 4; ++q) {
                        float2 f = __half22float2(w.hh[q]);
                        ac[q].x += f.x; ac[q].y += f.y;
                    }
                }
            }
        }
        float sc = dinv[nn] / (float)(c > 1 ? c : 1);
        const float2* ctr = (const float2*)(center2 + nn * F + 8 * h);
#pragma unroll
        for (int q = 0; q < 4; ++q) {
            float2 cv = ctr[q];
            float v0 = cv.x + ac[q].x * sc; v0 = v0 > 0.0f ? v0 : 0.0f;
            float v1 = cv.y + ac[q].y * sc; v1 = v1 > 0.0f ? v1 : 0.0f;
            tile[g][8 * h + 2 * q]     = v0;
            tile[g][8 * h + 2 * q + 1] = v1;
        }
    }
    if (h == 0) {
        int bb = -1;
        if (valid) bb = batch[nn];
        bid[g] = bb;
    }
    __syncthreads();
    if (threadIdx.x < 16) {
        int kk = threadIdx.x;
        int bcur = -2; float acc = 0.0f; int run = 0;
        for (int gg = 0; gg < PCHUNK; ++gg) {
            int b = bid[gg];
            if (b < 0) break;   // tail: invalid nodes only at the end
            if (b != bcur) {
                if (bcur >= 0) {
                    atomicAdd(&gpool[bcur * F + kk], acc);
                    if (kk == 0) atomicAdd(&gcnt[bcur], run);
                }
                acc = 0.0f; run = 0; bcur = b;
            }
            acc += tile[gg][kk];
            ++run;
        }
        if (bcur >= 0) {
            atomicAdd(&gpool[bcur * F + kk], acc);
            if (kk == 0) atomicAdd(&gcnt[bcur], run);
        }
    }
}

__global__ __launch_bounds__(64) void k_mlp(const float* __restrict__ gpool,
                                            const int* __restrict__ gcnt,
                                            const float* __restrict__ l1W,
                                            const float* __restrict__ l1b,
                                            const float* __restrict__ l2W,
                                            const float* __restrict__ l2b,
                                            float* __restrict__ out) {
    int g = threadIdx.x;
    if (g >= N_GRAPHS) return;
    int c = gcnt[g];
    float ic = 1.0f / (float)(c > 1 ? c : 1);
    float v[F], h[F];
#pragma unroll
    for (int k = 0; k < F; ++k) v[k] = gpool[g * F + k] * ic;
#pragma unroll
    for (int k = 0; k < F; ++k) {
        float a = l1b[k];
#pragma unroll
        for (int i = 0; i < F; ++i) a += v[i] * l1W[i * F + k];
        h[k] = a > 0.0f ? a : 0.0f;
    }
#pragma unroll
    for (int j = 0; j < 2; ++j) {
        float a = l2b[j];
#pragma unroll
        for (int i = 0; i < F; ++i) a += h[i] * l2W[i * 2 + j];
        out[g * 2 + j] = a;
    }
}

extern "C" void kernel_launch(void* const* d_in, const int* in_sizes, int n_in,
                              void* d_out, int out_size, void* d_ws, size_t ws_size,
                              hipStream_t stream) {
    const float* x     = (const float*)d_in[0];
    const int*   ei    = (const int*)d_in[1];
    const int*   row   = ei;
    const int*   col   = ei + N_EDGES;
    const int*   batch = (const int*)d_in[2];
    const float* c1W1  = (const float*)d_in[3];
    const float* c1b1  = (const float*)d_in[4];
    const float* c1W2  = (const float*)d_in[5];
    const float* c2W1  = (const float*)d_in[6];
    const float* c2b1  = (const float*)d_in[7];
    const float* c2W2  = (const float*)d_in[8];
    const float* l1W   = (const float*)d_in[9];
    const float* l1b   = (const float*)d_in[10];
    const float* l2W   = (const float*)d_in[11];
    const float* l2b   = (const float*)d_in[12];
    float* out = (float*)d_out;

    char* p = (char*)d_ws;
    auto alloc = [&p](size_t bytes) -> void* {
        void* r = (void*)p;
        p += (bytes + 255) & ~(size_t)255;
        return r;
    };
    float*          dinv    = (float*)         alloc(N_NODES * 4);
    float4*         wx      = (float4*)        alloc((size_t)N_NODES * 16);
    float*          center2 = (float*)         alloc((size_t)N_NODES * F * 4);
    __half*         xj2h    = (__half*)        alloc((size_t)N_NODES * F * 2);
    // gpool(4KB) + gcnt(256B) contiguous -> one memset
    float*          gpool   = (float*)         alloc(N_GRAPHS * F * 4);
    int*            gcnt    = (int*)           alloc(N_GRAPHS * 4);
    // bhistC(1KB) + bhistR(1KB) contiguous -> one memset
    int*            bhistC  = (int*)           alloc(NBUCK * 4);
    int*            bhistR  = (int*)           alloc(NBUCK * 4);
    int*            bbaseC  = (int*)           alloc((NBUCK + 1) * 4);
    int*            bbaseR  = (int*)           alloc((NBUCK + 1) * 4);
    int*            cntmatC = (int*)           alloc((size_t)NBUCK * NBLK * 4);
    int*            cntmatR = (int*)           alloc((size_t)NBUCK * NBLK * 4);
    int*            rowptr  = (int*)           alloc((size_t)N_NODES * 4);
    int*            cnt_in  = (int*)           alloc((size_t)N_NODES * 4);
    unsigned*       recsA   = (unsigned*)      alloc(((size_t)N_EDGES + NBUCK * 16) * 4);
    unsigned*       recsB   = (unsigned*)      alloc(((size_t)N_EDGES + NBUCK * 16) * 4);
    unsigned short* rrecs   = (unsigned short*)alloc(((size_t)N_EDGES + NBUCK * 16) * 2);

    hipMemsetAsync(gpool, 0, N_GRAPHS * F * 4 + 256, stream);     // gpool + gcnt
    hipMemsetAsync(bhistC, 0, 2 * NBUCK * 4, stream);             // bhistC + bhistR

    k_histAB<<<NBLK, 1024, 0, stream>>>(row, col, cntmatC, cntmatR, bhistC, bhistR);
    k_scans<<<2 * NBUCK + 2, 256, 0, stream>>>(cntmatC, cntmatR, bhistC, bhistR, bbaseC, bbaseR);
    k_fill3<<<NBLK, 1024, 0, stream>>>(row, col, cntmatC, cntmatR, bbaseC, bbaseR, recsA, rrecs);
    k_degsort<<<2 * NBUCK, 512, 0, stream>>>(recsA, bbaseC, bhistC, recsB, rowptr, cnt_in,
                                             rrecs, bbaseR, bhistR, x, dinv, wx);
    k_conv1<<<(N_NODES + 255) / 256, 256, 0, stream>>>(recsB, rowptr, cnt_in, dinv, wx, x,
                                                       c1W1, c1b1, c1W2, c2W1, c2b1, c2W2,
                                                       center2, xj2h);
    k_gpool<<<(N_NODES + PCHUNK - 1) / PCHUNK, 128, 0, stream>>>(
        recsB, rowptr, cnt_in, dinv, xj2h, center2, batch, gpool, gcnt);
    k_mlp<<<1, 64, 0, stream>>>(gpool, gcnt, l1W, l1b, l2W, l2b, out);
}